// Round 1
// baseline (523.430 us; speedup 1.0000x reference)
//
#include <hip/hip_runtime.h>

#define BATCH 256
#define SEQ_T 512
#define CIN   6
#define RES   256
// h padded: +4 dwords every 64 floats -> sub-chunks land on disjoint bank quads,
// and each chunk base stays 16B-aligned (272 dwords = 17 float4).
#define HPAD  272

// Quad-permute add via DPP: xor1 = quad_perm(1,0,3,2)=0xB1, xor2 = quad_perm(2,3,0,1)=0x4E
template <int CTRL>
__device__ __forceinline__ float quad_xor_add(float v) {
    union { float f; int i; } u;
    u.f = v;
    u.i = __builtin_amdgcn_mov_dpp(u.i, CTRL, 0xF, 0xF, true);
    return v + u.f;
}

// One workgroup (1024 threads = 16 waves) per batch row; loops over all T steps.
// Lane decomposition: wid = tid>>6 (wave), rr = lane>>2, sub = lane&3.
// Output r = wid*16+rr; lane owns k-chunk [sub*64, sub*64+64) of the dot product,
// W slice register-resident (64 VGPRs). Reduce across the 4 sub-lanes with 2 DPP
// quad-perm adds (no LDS, no extra barrier); every wave finishes its own 16 outputs.
// ONE raw s_barrier per step with lgkmcnt-only drain: global stores never waited.
__global__ __launch_bounds__(1024, 1)
void esn_scan_kernel(const float* __restrict__ x,
                     const float* __restrict__ W_in,
                     const float* __restrict__ W_res,
                     float* __restrict__ out) {
    __shared__ float h[2][HPAD];   // double-buffered state, padded

    const int tid  = threadIdx.x;
    const int b    = blockIdx.x;
    const int lane = tid & 63;
    const int wid  = tid >> 6;     // 0..15
    const int sub  = lane & 3;     // k-chunk selector
    const int rr   = lane >> 2;    // 0..15
    const int r    = (wid << 4) | rr;   // output index 0..255

    // Register-resident W slice: w[j] = W_res[(sub*64+j)][r]
    float w[64];
    #pragma unroll
    for (int j = 0; j < 64; ++j)
        w[j] = W_res[(sub * 64 + j) * RES + r];

    float win[CIN];
    #pragma unroll
    for (int c = 0; c < CIN; ++c) win[c] = W_in[c * RES + r];

    if (tid < RES) h[0][tid + ((tid >> 6) << 2)] = 0.0f;
    __syncthreads();

    const float* xb = x + (size_t)b * SEQ_T * CIN;
    float*       ob = out + (size_t)b * SEQ_T * RES + r;

    // padded indices
    const int wr = r + ((r >> 6) << 2);          // write slot of output r
    const float4* hA = (const float4*)&h[0][sub * 68];  // read base, buffer 0
    const float4* hB = (const float4*)&h[1][sub * 68];  // read base, buffer 1
    float* hAw = &h[0][wr];
    float* hBw = &h[1][wr];

#define ESN_STEP(HRD, HWR)                                              \
    {                                                                   \
        float xv[CIN];                                                  \
        _Pragma("unroll")                                               \
        for (int c = 0; c < CIN; ++c) xv[c] = xb[c];                    \
        xb += CIN;                                                      \
        float a0 = 0.f, a1 = 0.f, a2 = 0.f, a3 = 0.f;                   \
        _Pragma("unroll")                                               \
        for (int j = 0; j < 16; ++j) {                                  \
            float4 hv = (HRD)[j];                                       \
            a0 = fmaf(hv.x, w[4*j+0], a0);                              \
            a1 = fmaf(hv.y, w[4*j+1], a1);                              \
            a2 = fmaf(hv.z, w[4*j+2], a2);                              \
            a3 = fmaf(hv.w, w[4*j+3], a3);                              \
        }                                                               \
        float s = (a0 + a1) + (a2 + a3);                                \
        s = quad_xor_add<0xB1>(s);  /* + lane^1 */                      \
        s = quad_xor_add<0x4E>(s);  /* + lane^2 */                      \
        if (sub == 0) {                                                 \
            _Pragma("unroll")                                           \
            for (int c = 0; c < CIN; ++c) s = fmaf(xv[c], win[c], s);   \
            float e  = __expf(2.0f * s);                                \
            float hn = 1.0f - 2.0f * __builtin_amdgcn_rcpf(e + 1.0f);   \
            *(HWR) = hn;                                                \
            *ob = hn;                                                   \
        }                                                               \
        ob += RES;                                                      \
        asm volatile("s_waitcnt lgkmcnt(0)" ::: "memory");              \
        __builtin_amdgcn_s_barrier();                                   \
        asm volatile("" ::: "memory");                                  \
    }

    for (int t = 0; t < SEQ_T; t += 2) {
        ESN_STEP(hA, hBw);   // read h[0], write h[1]
        ESN_STEP(hB, hAw);   // read h[1], write h[0]
    }
#undef ESN_STEP
}

extern "C" void kernel_launch(void* const* d_in, const int* in_sizes, int n_in,
                              void* d_out, int out_size, void* d_ws, size_t ws_size,
                              hipStream_t stream) {
    const float* x     = (const float*)d_in[0];
    const float* W_in  = (const float*)d_in[1];
    const float* W_res = (const float*)d_in[2];
    float*       out   = (float*)d_out;

    esn_scan_kernel<<<BATCH, 1024, 0, stream>>>(x, W_in, W_res, out);
}

// Round 2
// 473.707 us; speedup vs baseline: 1.1050x; 1.1050x over previous
//
#include <hip/hip_runtime.h>

#define BATCH 256
#define SEQ_T 512
#define CIN   6
#define RES   256
// k split into 16 chunks of 16 floats; chunk stride padded to 20 dwords:
// banks of chunk s = (20s + d) % 32 -> at most 2-way aliasing (free), 16B-aligned (80B).
#define NCHUNK  16
#define CSTRIDE 20
#define HBUF    (NCHUNK * CSTRIDE)   // 320 dwords per buffer

// DPP rotate-right within 16-lane rows, fused into an add.
// row_ror:N ctrl = 0x120 + N.
template <int CTRL>
__device__ __forceinline__ float dpp_ror_add(float v) {
    union { float f; int i; } u;
    u.f = v;
    u.i = __builtin_amdgcn_mov_dpp(u.i, CTRL, 0xF, 0xF, true);
    return v + u.f;
}

// One workgroup (1024 threads = 16 waves) per batch row; loops over all T steps.
// Lane decomposition: wid = tid>>6, sub = lane&15 (k-chunk [sub*16,+16)),
// rg = lane>>4 (output group). Lane accumulates 4 outputs r = wid*16+rg*4+{0..3}
// over its 16-element k-chunk (64 reg-resident W values, 4 ds_read_b128/step).
// 16-lane all-reduce via 4 DPP row_ror adds (no LDS, no barrier). Lanes sub<4
// finish output rg*4+sub: x-proj + tanh + h/out writes.
// ONE raw s_barrier per step, lgkmcnt-only drain: global stores never waited.
__global__ __launch_bounds__(1024, 1)
void esn_scan_kernel(const float* __restrict__ x,
                     const float* __restrict__ W_in,
                     const float* __restrict__ W_res,
                     float* __restrict__ out) {
    __shared__ float h[2][HBUF];   // double-buffered state, padded

    const int tid  = threadIdx.x;
    const int b    = blockIdx.x;
    const int lane = tid & 63;
    const int wid  = tid >> 6;     // 0..15
    const int sub  = lane & 15;    // k-chunk selector
    const int rg   = lane >> 4;    // 0..3 output group within wave

    const int rbase = (wid << 4) | (rg << 2);   // first of this row's 4 outputs

    // Register-resident W slice: w[a][j] = W_res[sub*16+j][rbase+a]
    float w[4][16];
    #pragma unroll
    for (int a = 0; a < 4; ++a)
        #pragma unroll
        for (int j = 0; j < 16; ++j)
            w[a][j] = W_res[(sub * 16 + j) * RES + rbase + a];

    const int ract = rbase + (sub & 3);         // output this lane writes (if sub<4)
    float win[CIN];
    #pragma unroll
    for (int c = 0; c < CIN; ++c) win[c] = W_in[c * RES + ract];

    if (tid < HBUF) h[0][tid] = 0.0f;
    __syncthreads();

    const float* xb = x + (size_t)b * SEQ_T * CIN;
    float*       ob = out + (size_t)b * SEQ_T * RES + ract;

    const float4* hr0 = (const float4*)&h[0][sub * CSTRIDE];
    const float4* hr1 = (const float4*)&h[1][sub * CSTRIDE];
    const int wslot = wid * CSTRIDE + (rg << 2) + (sub & 3);
    float* hw0 = &h[0][wslot];
    float* hw1 = &h[1][wslot];
    const bool writer = (sub < 4);

#define ESN_STEP(HRD, HWR)                                              \
    {                                                                   \
        float4 h0 = (HRD)[0], h1 = (HRD)[1], h2 = (HRD)[2], h3 = (HRD)[3]; \
        float xv[CIN];                                                  \
        _Pragma("unroll")                                               \
        for (int c = 0; c < CIN; ++c) xv[c] = xb[c];   /* uniform -> s_load */ \
        xb += CIN;                                                      \
        float acc[4];                                                   \
        _Pragma("unroll")                                               \
        for (int a = 0; a < 4; ++a) {                                   \
            float s0 = h0.x * w[a][0];                                  \
            s0 = fmaf(h0.y, w[a][1], s0);                               \
            s0 = fmaf(h0.z, w[a][2], s0);                               \
            s0 = fmaf(h0.w, w[a][3], s0);                               \
            float s1 = h1.x * w[a][4];                                  \
            s1 = fmaf(h1.y, w[a][5], s1);                               \
            s1 = fmaf(h1.z, w[a][6], s1);                               \
            s1 = fmaf(h1.w, w[a][7], s1);                               \
            float s2 = h2.x * w[a][8];                                  \
            s2 = fmaf(h2.y, w[a][9],  s2);                              \
            s2 = fmaf(h2.z, w[a][10], s2);                              \
            s2 = fmaf(h2.w, w[a][11], s2);                              \
            float s3 = h3.x * w[a][12];                                 \
            s3 = fmaf(h3.y, w[a][13], s3);                              \
            s3 = fmaf(h3.z, w[a][14], s3);                              \
            s3 = fmaf(h3.w, w[a][15], s3);                              \
            acc[a] = (s0 + s1) + (s2 + s3);                             \
        }                                                               \
        /* 16-lane all-reduce: 4 DPP row_ror stages, 4 accs interleaved */ \
        _Pragma("unroll")                                               \
        for (int a = 0; a < 4; ++a) acc[a] = dpp_ror_add<0x128>(acc[a]); \
        _Pragma("unroll")                                               \
        for (int a = 0; a < 4; ++a) acc[a] = dpp_ror_add<0x124>(acc[a]); \
        _Pragma("unroll")                                               \
        for (int a = 0; a < 4; ++a) acc[a] = dpp_ror_add<0x122>(acc[a]); \
        _Pragma("unroll")                                               \
        for (int a = 0; a < 4; ++a) acc[a] = dpp_ror_add<0x121>(acc[a]); \
        float s = acc[0];                                               \
        s = (sub == 1) ? acc[1] : s;                                    \
        s = (sub == 2) ? acc[2] : s;                                    \
        s = (sub == 3) ? acc[3] : s;                                    \
        if (writer) {                                                   \
            _Pragma("unroll")                                           \
            for (int c = 0; c < CIN; ++c) s = fmaf(xv[c], win[c], s);   \
            float e  = __expf(2.0f * s);                                \
            float hn = 1.0f - 2.0f * __builtin_amdgcn_rcpf(e + 1.0f);   \
            *(HWR) = hn;                                                \
            *ob = hn;                                                   \
        }                                                               \
        ob += RES;                                                      \
        asm volatile("s_waitcnt lgkmcnt(0)" ::: "memory");              \
        __builtin_amdgcn_s_barrier();                                   \
        asm volatile("" ::: "memory");                                  \
    }

    for (int t = 0; t < SEQ_T; t += 2) {
        ESN_STEP(hr0, hw1);   // read h[0], write h[1]
        ESN_STEP(hr1, hw0);   // read h[1], write h[0]
    }
#undef ESN_STEP
}

extern "C" void kernel_launch(void* const* d_in, const int* in_sizes, int n_in,
                              void* d_out, int out_size, void* d_ws, size_t ws_size,
                              hipStream_t stream) {
    const float* x     = (const float*)d_in[0];
    const float* W_in  = (const float*)d_in[1];
    const float* W_res = (const float*)d_in[2];
    float*       out   = (float*)d_out;

    esn_scan_kernel<<<BATCH, 1024, 0, stream>>>(x, W_in, W_res, out);
}

// Round 3
// 466.171 us; speedup vs baseline: 1.1228x; 1.0162x over previous
//
#include <hip/hip_runtime.h>

#define BATCH 256
#define SEQ_T 512
#define CIN   6
#define RES   256
// k split into 8 chunks of 32 floats; chunk stride padded to 36 dwords:
// chunk s base bank = (36s)%32 = 4s%32 -> 8 chunks cover banks {0,4,...,28},
// instruction j across the wave reads 8 distinct addresses on disjoint bank
// quads (each broadcast to 8 lanes) -> conflict-free. 16B-aligned (144B).
#define NCH     8
#define CSTRIDE 36
#define HBUF    (NCH * CSTRIDE)   // 288 dwords per buffer

typedef float f32x2 __attribute__((ext_vector_type(2)));

// Packed fp32 FMA (VOP3P): d.lo = a.lo*b.lo + c.lo, d.hi = a.hi*b.hi + c.hi
__device__ __forceinline__ f32x2 pk_fma(f32x2 a, f32x2 b, f32x2 c) {
    f32x2 d;
    asm("v_pk_fma_f32 %0, %1, %2, %3" : "=v"(d) : "v"(a), "v"(b), "v"(c));
    return d;
}

// DPP permute fused into an add. 0xB1=quad xor1, 0x4E=quad xor2,
// 0x141=row_half_mirror (crosses the two quads inside each 8-lane group).
template <int CTRL>
__device__ __forceinline__ float dpp_add(float v) {
    union { float f; int i; } u;
    u.f = v;
    u.i = __builtin_amdgcn_mov_dpp(u.i, CTRL, 0xF, 0xF, true);
    return v + u.f;
}

// One workgroup (1024 threads = 16 waves) per batch row; loops over all T steps.
// Lane decomposition: wid = tid>>6, sub = lane&7 (k-chunk [sub*32,+32)),
// rg = lane>>3 (0..7, output pair rbase = wid*16+rg*2). Lane accumulates the
// pair over its 32-element k-chunk with 32 v_pk_fma_f32 (64 reg-resident W
// values as f32x2 pairs, 8 ds_read_b128/step). 8-lane all-reduce = 3 DPP-add
// stages (no LDS, no barrier). Lanes sub<2 finish output rbase+(sub&1):
// x-proj + tanh + h/out writes. x is register-prefetched one step ahead.
// ONE raw s_barrier per step, lgkmcnt-only drain: global stores never waited.
__global__ __launch_bounds__(1024, 1)
void esn_scan_kernel(const float* __restrict__ x,
                     const float* __restrict__ W_in,
                     const float* __restrict__ W_res,
                     float* __restrict__ out) {
    __shared__ float h[2][HBUF];   // double-buffered state, padded

    const int tid  = threadIdx.x;
    const int b    = blockIdx.x;
    const int lane = tid & 63;
    const int wid  = tid >> 6;     // 0..15
    const int sub  = lane & 7;     // k-chunk selector
    const int rg   = lane >> 3;    // 0..7 output-pair group

    const int rbase = (wid << 4) | (rg << 1);   // first of this lane's 2 outputs

    // Register-resident W slice as packed pairs:
    // w2[a][j] = { W_res[sub*32+2j][rbase+a], W_res[sub*32+2j+1][rbase+a] }
    f32x2 w2[2][16];
    #pragma unroll
    for (int a = 0; a < 2; ++a)
        #pragma unroll
        for (int j = 0; j < 16; ++j) {
            f32x2 p;
            p.x = W_res[(sub * 32 + 2 * j)     * RES + rbase + a];
            p.y = W_res[(sub * 32 + 2 * j + 1) * RES + rbase + a];
            w2[a][j] = p;
        }

    const int ract = rbase + (sub & 1);         // output this lane writes (if sub<2)
    float win[CIN];
    #pragma unroll
    for (int c = 0; c < CIN; ++c) win[c] = W_in[c * RES + ract];

    if (tid < HBUF) h[0][tid] = 0.0f;
    __syncthreads();

    const float* xb = x + (size_t)b * SEQ_T * CIN;
    float*       ob = out + (size_t)b * SEQ_T * RES + ract;

    const float4* hr0 = (const float4*)&h[0][sub * CSTRIDE];
    const float4* hr1 = (const float4*)&h[1][sub * CSTRIDE];
    const int wslot = ((ract >> 5) * CSTRIDE) + (ract & 31);
    float* hw0 = &h[0][wslot];
    float* hw1 = &h[1][wslot];
    const bool writer = (sub < 2);

    // x prefetch buffers (uniform loads -> scalarized by the compiler)
    float xA[CIN], xB[CIN];
    #pragma unroll
    for (int c = 0; c < CIN; ++c) xA[c] = xb[c];
    xb += CIN;

#define ESN_STEP(HRD, HWR, XC, XN, PREF)                                \
    {                                                                   \
        float4 hv[NCH];                                                 \
        _Pragma("unroll")                                               \
        for (int j = 0; j < NCH; ++j) hv[j] = (HRD)[j];                 \
        if (PREF) {                                                     \
            _Pragma("unroll")                                           \
            for (int c = 0; c < CIN; ++c) (XN)[c] = xb[c];              \
            xb += CIN;                                                  \
        }                                                               \
        f32x2 acc0 = {0.f, 0.f}, acc1 = {0.f, 0.f};                    \
        _Pragma("unroll")                                               \
        for (int j = 0; j < NCH; ++j) {                                 \
            f32x2 plo, phi;                                             \
            plo.x = hv[j].x; plo.y = hv[j].y;                           \
            phi.x = hv[j].z; phi.y = hv[j].w;                           \
            acc0 = pk_fma(plo, w2[0][2 * j],     acc0);                 \
            acc0 = pk_fma(phi, w2[0][2 * j + 1], acc0);                 \
            acc1 = pk_fma(plo, w2[1][2 * j],     acc1);                 \
            acc1 = pk_fma(phi, w2[1][2 * j + 1], acc1);                 \
        }                                                               \
        float a0 = acc0.x + acc0.y;                                     \
        float a1 = acc1.x + acc1.y;                                     \
        a0 = dpp_add<0xB1>(a0);  a1 = dpp_add<0xB1>(a1);                \
        a0 = dpp_add<0x4E>(a0);  a1 = dpp_add<0x4E>(a1);                \
        a0 = dpp_add<0x141>(a0); a1 = dpp_add<0x141>(a1);               \
        float s = (sub & 1) ? a1 : a0;                                  \
        if (writer) {                                                   \
            _Pragma("unroll")                                           \
            for (int c = 0; c < CIN; ++c) s = fmaf((XC)[c], win[c], s); \
            float e  = __expf(2.0f * s);                                \
            float hn = 1.0f - 2.0f * __builtin_amdgcn_rcpf(e + 1.0f);   \
            *(HWR) = hn;                                                \
            *ob = hn;                                                   \
        }                                                               \
        ob += RES;                                                      \
        asm volatile("s_waitcnt lgkmcnt(0)" ::: "memory");              \
        __builtin_amdgcn_s_barrier();                                   \
        asm volatile("" ::: "memory");                                  \
    }

    // Main loop: t = 0..509 with prefetch (max prefetch index 510 < 512).
    for (int t = 0; t < SEQ_T - 2; t += 2) {
        ESN_STEP(hr0, hw1, xA, xB, 1);   // read h[0], write h[1]
        ESN_STEP(hr1, hw0, xB, xA, 1);   // read h[1], write h[0]
    }
    ESN_STEP(hr0, hw1, xA, xB, 1);       // t=510, prefetches x[511]
    ESN_STEP(hr1, hw0, xB, xA, 0);       // t=511, no prefetch
#undef ESN_STEP
}

extern "C" void kernel_launch(void* const* d_in, const int* in_sizes, int n_in,
                              void* d_out, int out_size, void* d_ws, size_t ws_size,
                              hipStream_t stream) {
    const float* x     = (const float*)d_in[0];
    const float* W_in  = (const float*)d_in[1];
    const float* W_res = (const float*)d_in[2];
    float*       out   = (float*)d_out;

    esn_scan_kernel<<<BATCH, 1024, 0, stream>>>(x, W_in, W_res, out);
}

// Round 4
// 431.109 us; speedup vs baseline: 1.2141x; 1.0813x over previous
//
#include <hip/hip_runtime.h>

#define BATCH 256
#define SEQ_T 512
#define CIN   6
#define RES   256
// h stored as 16 chunks of 16 floats; chunk stride padded to 20 dwords (80 B,
// 16B-aligned). Read inst j: 16 distinct addresses (one per sub), each
// broadcast to 4 lanes; bases 20s%32 tile banks 2-way -> free (R2 measured 0).
#define NCH     16
#define CSTRIDE 20
#define HBUF    (NCH * CSTRIDE)   // 320 dwords per buffer

typedef float f32x2 __attribute__((ext_vector_type(2)));

// Packed fp32 FMA (VOP3P, full-rate per R3 measurement).
__device__ __forceinline__ f32x2 pk_fma(f32x2 a, f32x2 b, f32x2 c) {
    f32x2 d;
    asm("v_pk_fma_f32 %0, %1, %2, %3" : "=v"(d) : "v"(a), "v"(b), "v"(c));
    return d;
}

// v + dpp<CTRL>(v)
template <int CTRL>
__device__ __forceinline__ float dpp_add(float v) {
    union { float f; int i; } u;
    u.f = v;
    u.i = __builtin_amdgcn_mov_dpp(u.i, CTRL, 0xF, 0xF, true);
    return v + u.f;
}

// keep + dpp<CTRL>(give)  (butterfly stage with index splitting)
template <int CTRL>
__device__ __forceinline__ float dpp_xadd(float keep, float give) {
    union { float f; int i; } u;
    u.f = give;
    u.i = __builtin_amdgcn_mov_dpp(u.i, CTRL, 0xF, 0xF, true);
    return keep + u.f;
}

// One workgroup (512 threads = 8 waves) per batch row -> 1 block/CU, half the
// h-replication LDS traffic of the 16-wave variant (LDS return BW was the
// dominant per-step cost). Lane decomposition: wid=tid>>6 (0..7),
// g=(lane>>4)&3 (group), sub=lane&15 (k-chunk [sub*16,+16), 4 ds_read_b128).
// Group (wid,g) owns 8 outputs rbase=32*wid+8*g .. +7; each lane accumulates
// all 8 over its 16 k-values with 64 v_pk_fma_f32 (128 reg-resident W floats).
// 16-lane reduce: butterfly xor1,xor2,row_ror4,row_ror8 keyed on lane bits
// 0/1/2 -> lane l ends holding the full sum for output a=l&7 (no final
// select). Lanes sub<8 finish output rbase+a: x-proj + tanh + h/out writes.
// ONE raw s_barrier per step, lgkmcnt-only drain: global stores never waited.
__global__ __launch_bounds__(512, 2)
void esn_scan_kernel(const float* __restrict__ x,
                     const float* __restrict__ W_in,
                     const float* __restrict__ W_res,
                     float* __restrict__ out) {
    __shared__ float h[2][HBUF];   // double-buffered state, padded

    const int tid  = threadIdx.x;
    const int b    = blockIdx.x;
    const int lane = tid & 63;
    const int wid  = tid >> 6;     // 0..7
    const int sub  = lane & 15;    // k-chunk selector
    const int g    = lane >> 4;    // 0..3 group within wave
    const int a    = lane & 7;     // output index this lane finalizes

    const int rbase = 32 * wid + 8 * g;   // group's first output
    const int ract  = rbase + a;          // output this lane writes (if sub<8)

    // Register-resident W slice as packed pairs:
    // w2[o][m] = { W_res[sub*16+2m][rbase+o], W_res[sub*16+2m+1][rbase+o] }
    f32x2 w2[8][8];
    #pragma unroll
    for (int o = 0; o < 8; ++o)
        #pragma unroll
        for (int m = 0; m < 8; ++m) {
            f32x2 p;
            p.x = W_res[(sub * 16 + 2 * m)     * RES + rbase + o];
            p.y = W_res[(sub * 16 + 2 * m + 1) * RES + rbase + o];
            w2[o][m] = p;
        }

    float win[CIN];
    #pragma unroll
    for (int c = 0; c < CIN; ++c) win[c] = W_in[c * RES + ract];

    if (tid < HBUF) h[0][tid] = 0.0f;
    __syncthreads();

    const float* xb = x + (size_t)b * SEQ_T * CIN;
    float*       ob = out + (size_t)b * SEQ_T * RES + ract;

    const float4* hr0 = (const float4*)&h[0][sub * CSTRIDE];
    const float4* hr1 = (const float4*)&h[1][sub * CSTRIDE];
    const int wslot = ((ract >> 4) * CSTRIDE) + (ract & 15);
    float* hw0 = &h[0][wslot];
    float* hw1 = &h[1][wslot];
    const bool writer = (sub < 8);
    const bool p0 = (lane & 1) != 0;
    const bool p1 = (lane & 2) != 0;
    const bool p2 = (lane & 4) != 0;

    // x prefetch buffers (uniform -> scalarized)
    float xA[CIN], xB[CIN];
    #pragma unroll
    for (int c = 0; c < CIN; ++c) xA[c] = xb[c];
    xb += CIN;

#define ESN_STEP(HRD, HWR, XC, XN, PREF)                                \
    {                                                                   \
        float4 hv0 = (HRD)[0], hv1 = (HRD)[1], hv2 = (HRD)[2], hv3 = (HRD)[3]; \
        if (PREF) {                                                     \
            _Pragma("unroll")                                           \
            for (int c = 0; c < CIN; ++c) (XN)[c] = xb[c];              \
            xb += CIN;                                                  \
        }                                                               \
        f32x2 hp[8];                                                    \
        hp[0].x = hv0.x; hp[0].y = hv0.y; hp[1].x = hv0.z; hp[1].y = hv0.w; \
        hp[2].x = hv1.x; hp[2].y = hv1.y; hp[3].x = hv1.z; hp[3].y = hv1.w; \
        hp[4].x = hv2.x; hp[4].y = hv2.y; hp[5].x = hv2.z; hp[5].y = hv2.w; \
        hp[6].x = hv3.x; hp[6].y = hv3.y; hp[7].x = hv3.z; hp[7].y = hv3.w; \
        float s0, s1, s2, s3, s4, s5, s6, s7;                           \
        {                                                               \
            f32x2 acc[8];                                               \
            _Pragma("unroll")                                           \
            for (int o = 0; o < 8; ++o) {                               \
                f32x2 t = {0.f, 0.f};                                   \
                _Pragma("unroll")                                       \
                for (int m = 0; m < 8; ++m) t = pk_fma(hp[m], w2[o][m], t); \
                acc[o] = t;                                             \
            }                                                           \
            s0 = acc[0].x + acc[0].y; s1 = acc[1].x + acc[1].y;         \
            s2 = acc[2].x + acc[2].y; s3 = acc[3].x + acc[3].y;         \
            s4 = acc[4].x + acc[4].y; s5 = acc[5].x + acc[5].y;         \
            s6 = acc[6].x + acc[6].y; s7 = acc[7].x + acc[7].y;         \
        }                                                               \
        /* 16-lane butterfly reduce; lane l ends with sum for a=l&7 */  \
        float t0 = dpp_xadd<0xB1>(p0 ? s1 : s0, p0 ? s0 : s1);          \
        float t1 = dpp_xadd<0xB1>(p0 ? s3 : s2, p0 ? s2 : s3);          \
        float t2 = dpp_xadd<0xB1>(p0 ? s5 : s4, p0 ? s4 : s5);          \
        float t3 = dpp_xadd<0xB1>(p0 ? s7 : s6, p0 ? s6 : s7);          \
        float u0 = dpp_xadd<0x4E>(p1 ? t1 : t0, p1 ? t0 : t1);          \
        float u1 = dpp_xadd<0x4E>(p1 ? t3 : t2, p1 ? t2 : t3);          \
        float v  = dpp_xadd<0x124>(p2 ? u1 : u0, p2 ? u0 : u1);         \
        float s  = dpp_add<0x128>(v);                                   \
        if (writer) {                                                   \
            _Pragma("unroll")                                           \
            for (int c = 0; c < CIN; ++c) s = fmaf((XC)[c], win[c], s); \
            float e  = __expf(2.0f * s);                                \
            float hn = 1.0f - 2.0f * __builtin_amdgcn_rcpf(e + 1.0f);   \
            *(HWR) = hn;                                                \
            *ob = hn;                                                   \
        }                                                               \
        ob += RES;                                                      \
        asm volatile("s_waitcnt lgkmcnt(0)" ::: "memory");              \
        __builtin_amdgcn_s_barrier();                                   \
        asm volatile("" ::: "memory");                                  \
    }

    // Main loop: unroll-2 over the double buffer; prefetch x one step ahead.
    for (int t = 0; t < SEQ_T - 2; t += 2) {
        ESN_STEP(hr0, hw1, xA, xB, 1);   // read h[0], write h[1]
        ESN_STEP(hr1, hw0, xB, xA, 1);   // read h[1], write h[0]
    }
    ESN_STEP(hr0, hw1, xA, xB, 1);       // t=510, prefetches x[511]
    ESN_STEP(hr1, hw0, xB, xA, 0);       // t=511, no prefetch
#undef ESN_STEP
}

extern "C" void kernel_launch(void* const* d_in, const int* in_sizes, int n_in,
                              void* d_out, int out_size, void* d_ws, size_t ws_size,
                              hipStream_t stream) {
    const float* x     = (const float*)d_in[0];
    const float* W_in  = (const float*)d_in[1];
    const float* W_res = (const float*)d_in[2];
    float*       out   = (float*)d_out;

    esn_scan_kernel<<<BATCH, 512, 0, stream>>>(x, W_in, W_res, out);
}